// Round 1
// baseline (188790.942 us; speedup 1.0000x reference)
//
#include <hip/hip_runtime.h>
#include <math.h>

// ---------------- problem constants ----------------
#define TBATCH 32
#define TMEM   200
#define TSTEPS 400
#define DENC   512
#define DL     1024
#define G4     4096   // 4*DL
#define DATT   128
#define DPRE   256
#define NMEL   80
#define K1     1792   // 256 (x) + 512 (ctx) + 1024 (h1)
#define KSPL1  768    // rows in lstm1_k
#define KC1    112    // K1/16
#define K2     2560   // 1024 (h1) + 512 (ctx) + 1024 (h2)
#define KSPL2  1536   // rows in lstm2_k
#define KC2    160    // K2/16

#define NBLK 256
#define NTHR 256

// ---------------- workspace layout (float offsets) ----------------
#define OFF_XPRE  0u
#define SZ_XPRE   (400u*32u*256u)            // prenet outputs [t][b][256]
#define OFF_PM    (OFF_XPRE + SZ_XPRE)
#define SZ_PM     (32u*200u*128u)            // tanh(memory@wm) [b][t][128]
#define OFF_IN1T  (OFF_PM + SZ_PM)
#define SZ_IN1T   (1792u*32u)                // lstm1 input, transposed [k][b]
#define OFF_IN2T  (OFF_IN1T + SZ_IN1T)
#define SZ_IN2T   (2560u*32u)                // lstm2 input, transposed [k][b]
#define OFF_ZP    (OFF_IN2T + SZ_IN2T)
#define SZ_ZP     (16u*32u*4096u)            // gate partials [kc][b][4096]
#define OFF_C1    (OFF_ZP + SZ_ZP)           // c1 [b][1024]
#define OFF_C2    (OFF_C1 + 32768u)          // c2
#define OFF_CTX   (OFF_C2 + 32768u)          // ctx [b][512]
#define OFF_ATTW  (OFF_CTX + 16384u)         // att_w [b][200]
#define OFF_CUM   (OFF_ATTW + 6400u)         // att_w_cum
#define OFF_EEXP  (OFF_CUM + 6400u)          // exp(energies)
#define OFF_Q     (OFF_EEXP + 6400u)         // q [b][128]
#define OFF_DEN   (OFF_Q + 4096u)            // softmax denom [b]
#define OFF_BAR   (OFF_DEN + 32u)            // barrier words
#define WS_FLOATS (OFF_BAR + 16u)

// output layout (floats)
#define OUT_GATE  1024000   // 32*80*400
#define OUT_ALIGN 1036800   // + 32*400

__device__ __forceinline__ float sigf(float x)   { return 1.f / (1.f + __expf(-x)); }
__device__ __forceinline__ float tanhf_(float x) { return 1.f - 2.f / (__expf(2.f*x) + 1.f); }

// ---------------- grid barrier (all blocks resident: grid=256 <= 256 CUs) ----------------
__device__ __forceinline__ void grid_barrier(unsigned* bar, unsigned* gen) {
    __syncthreads();
    if (threadIdx.x == 0) {
        __threadfence();  // release: writeback L2 so other XCDs see our stores
        unsigned g = __hip_atomic_load(gen, __ATOMIC_RELAXED, __HIP_MEMORY_SCOPE_AGENT);
        unsigned t = __hip_atomic_fetch_add(bar, 1u, __ATOMIC_ACQ_REL, __HIP_MEMORY_SCOPE_AGENT);
        if (t == (unsigned)(NBLK - 1)) {
            __hip_atomic_store(bar, 0u, __ATOMIC_RELAXED, __HIP_MEMORY_SCOPE_AGENT);
            __hip_atomic_store(gen, g + 1u, __ATOMIC_RELEASE, __HIP_MEMORY_SCOPE_AGENT);
        } else {
            while (__hip_atomic_load(gen, __ATOMIC_RELAXED, __HIP_MEMORY_SCOPE_AGENT) == g)
                __builtin_amdgcn_s_sleep(2);
        }
        __threadfence();  // acquire: invalidate L1/L2 stale lines
    }
    __syncthreads();
}

// ---------------- P1: prenet for all 400 frames ----------------
__global__ void __launch_bounds__(256) prenet_kernel(
    const float* __restrict__ dec, const float* __restrict__ w0, const float* __restrict__ b0,
    const float* __restrict__ w1, const float* __restrict__ b1, float* __restrict__ ws)
{
    __shared__ float s_in[80];
    __shared__ float s_h0[256];
    int t = blockIdx.x, b = blockIdx.y, tid = threadIdx.x;
    if (tid < 80) s_in[tid] = (t == 0) ? 0.f : dec[b*32000 + tid*400 + (t-1)];
    if (blockIdx.x == 0 && blockIdx.y == 0 && tid < 4)
        ((unsigned*)(ws + OFF_BAR))[tid] = 0u;   // zero barrier words each call
    __syncthreads();
    float s = b0[tid];
    for (int m = 0; m < 80; ++m) s = fmaf(s_in[m], w0[m*256 + tid], s);
    s_h0[tid] = fmaxf(s, 0.f);
    __syncthreads();
    float s2 = b1[tid];
    for (int k = 0; k < 256; ++k) s2 = fmaf(s_h0[k], w1[k*256 + tid], s2);
    ws[OFF_XPRE + (t*32 + b)*256 + tid] = fmaxf(s2, 0.f);
}

// ---------------- P2: processed_memory = tanh(memory @ wm) ----------------
__global__ void __launch_bounds__(128) pmem_kernel(
    const float* __restrict__ mp, const float* __restrict__ wm, float* __restrict__ ws)
{
    int t = blockIdx.x, b = blockIdx.y, a = threadIdx.x;
    const float* mrow = mp + (b*200 + t)*512;
    float s = 0.f;
    for (int d = 0; d < 512; ++d) s = fmaf(mrow[d], wm[d*128 + a], s);
    ws[OFF_PM + (b*200 + t)*128 + a] = tanhf_(s);
}

// ---------------- GEMV partial: z_partial[kc][b][j] += sum_k inT[k][b]*W[k][j] ----------------
__device__ __forceinline__ void gemv_block(
    const float* __restrict__ Wk, const float* __restrict__ Wr, int ksplit,
    const float* __restrict__ inT, float* __restrict__ zp, int kcsize)
{
    int jb = blockIdx.x >> 4, kc = blockIdx.x & 15;
    int j = (jb << 8) + threadIdx.x;
    float acc[32];
#pragma unroll
    for (int i = 0; i < 32; ++i) acc[i] = 0.f;
    int k0 = kc * kcsize, k1 = k0 + kcsize;
    int ka = min(k1, ksplit);
    for (int k = k0; k < ka; ++k) {
        float w = Wk[k*4096 + j];
        const float4* iv = (const float4*)(inT + k*32);
#pragma unroll
        for (int bb = 0; bb < 8; ++bb) {
            float4 x = iv[bb];
            acc[bb*4+0] = fmaf(x.x, w, acc[bb*4+0]);
            acc[bb*4+1] = fmaf(x.y, w, acc[bb*4+1]);
            acc[bb*4+2] = fmaf(x.z, w, acc[bb*4+2]);
            acc[bb*4+3] = fmaf(x.w, w, acc[bb*4+3]);
        }
    }
    int kb = max(k0, ksplit);
    for (int k = kb; k < k1; ++k) {
        float w = Wr[(k - ksplit)*4096 + j];
        const float4* iv = (const float4*)(inT + k*32);
#pragma unroll
        for (int bb = 0; bb < 8; ++bb) {
            float4 x = iv[bb];
            acc[bb*4+0] = fmaf(x.x, w, acc[bb*4+0]);
            acc[bb*4+1] = fmaf(x.y, w, acc[bb*4+1]);
            acc[bb*4+2] = fmaf(x.z, w, acc[bb*4+2]);
            acc[bb*4+3] = fmaf(x.w, w, acc[bb*4+3]);
        }
    }
    float* zr = zp + (kc*32)*4096 + j;
#pragma unroll
    for (int b = 0; b < 32; ++b) zr[b*4096] = acc[b];
}

// ---------------- persistent decoder loop ----------------
__global__ void __launch_bounds__(256) decoder_loop(
    const float* __restrict__ mp,
    const float* __restrict__ l1k, const float* __restrict__ l1r, const float* __restrict__ l1b,
    const float* __restrict__ l2k, const float* __restrict__ l2r, const float* __restrict__ l2b,
    const float* __restrict__ wq, const float* __restrict__ vvec,
    const float* __restrict__ lconv, const float* __restrict__ ldense,
    const float* __restrict__ fw, const float* __restrict__ fb,
    const float* __restrict__ sw, const float* __restrict__ sb,
    float* __restrict__ ws, float* __restrict__ out)
{
    // persistent LDS (loaded once; blocks are resident for the whole kernel)
    __shared__ float s_convw[31*2*32];
    __shared__ float s_ldense[32*128];
    __shared__ float s_v[128];
    // scratch
    __shared__ float s_wwin[56], s_cwin[56];
    __shared__ float s_co[25*33];
    __shared__ float s_ea[25*128];
    __shared__ float s_q[128];
    __shared__ float s_ex[32];
    __shared__ float s_hid[1024];
    __shared__ float s_red[256];

    float* xpre = ws + OFF_XPRE;
    float* pm   = ws + OFF_PM;
    float* in1T = ws + OFF_IN1T;
    float* in2T = ws + OFF_IN2T;
    float* zp   = ws + OFF_ZP;
    float* c1a  = ws + OFF_C1;
    float* c2a  = ws + OFF_C2;
    float* ctx  = ws + OFF_CTX;
    float* attw = ws + OFF_ATTW;
    float* cum  = ws + OFF_CUM;
    float* eexp = ws + OFF_EEXP;
    float* qarr = ws + OFF_Q;
    float* den  = ws + OFF_DEN;
    unsigned* bar = (unsigned*)(ws + OFF_BAR);
    unsigned* gen = bar + 1;

    const int tid = threadIdx.x;
    const int gid = blockIdx.x * NTHR + tid;
    const int gsz = NBLK * NTHR;

    // persistent LDS fill
    for (int i = tid; i < 1984; i += NTHR) s_convw[i] = lconv[i];
    for (int i = tid; i < 4096; i += NTHR) s_ldense[i] = ldense[i];
    if (tid < 128) s_v[tid] = vvec[tid];

    // ---- init (ws is poisoned before every call) ----
    for (int i = gid; i < (int)SZ_IN1T - 256*32; i += gsz) in1T[256*32 + i] = 0.f; // ctx+h1 rows
    for (int i = gid; i < (int)SZ_IN2T; i += gsz) in2T[i] = 0.f;
    for (int i = gid; i < 32768; i += gsz) { c1a[i] = 0.f; c2a[i] = 0.f; }
    for (int i = gid; i < 6400;  i += gsz) { attw[i] = 0.f; cum[i] = 0.f; }
    for (int i = gid; i < 8192;  i += gsz) {                 // x rows for t=0
        int k = i >> 5, b = i & 31;
        in1T[i] = xpre[b*256 + k];
    }
    grid_barrier(bar, gen);

#pragma unroll 1
    for (int t = 0; t < TSTEPS; ++t) {
        // ---- S1: LSTM1 gate partials ----
        gemv_block(l1k, l1r, KSPL1, in1T, zp, KC1);
        grid_barrier(bar, gen);

        // ---- S2: reduce -> gates -> h1,c1 ; q = tanh(h1@wq) ; zero denom ----
        if (blockIdx.x < 32) {
            int b = blockIdx.x;
            for (int u = tid; u < 1024; u += NTHR) {
                float zi = l1b[u], zf = l1b[1024+u], zg = l1b[2048+u], zo = l1b[3072+u];
                for (int kc = 0; kc < 16; ++kc) {
                    const float* zr = zp + (kc*32 + b)*4096;
                    zi += zr[u]; zf += zr[1024+u]; zg += zr[2048+u]; zo += zr[3072+u];
                }
                float c = sigf(zf)*c1a[b*1024+u] + sigf(zi)*tanhf_(zg);
                float h = sigf(zo)*tanhf_(c);
                c1a[b*1024+u] = c;
                in1T[(768+u)*32 + b] = h;    // next step's h-rows
                in2T[u*32 + b] = h;          // lstm2 input rows 0..1023
                s_hid[u] = h;
            }
            if (tid == 0) den[b] = 0.f;
            __syncthreads();
            int a = tid & 127, hf = tid >> 7;
            float s = 0.f;
            for (int u = hf*512; u < hf*512 + 512; ++u) s = fmaf(s_hid[u], wq[u*128 + a], s);
            s_red[tid] = s;
            __syncthreads();
            if (tid < 128) qarr[b*128 + tid] = tanhf_(s_red[tid] + s_red[128 + tid]);
        }
        grid_barrier(bar, gen);

        // ---- S3: location attention -> exp(energies), partial denom ----
        {
            int b = blockIdx.x >> 3, tc = blockIdx.x & 7;
            int t0 = tc * 25;
            if (tid < 56)      { int tg = t0 - 15 + tid;      s_wwin[tid]    = (tg >= 0 && tg < 200) ? attw[b*200 + tg] : 0.f; }
            else if (tid < 112){ int i = tid - 56; int tg = t0 - 15 + i; s_cwin[i] = (tg >= 0 && tg < 200) ? cum[b*200 + tg] : 0.f; }
            else if (tid < 240 && tid >= 112) { int a = tid - 112; if (a < 128) s_q[a] = qarr[b*128 + a]; }
            __syncthreads();
            for (int idx = tid; idx < 800; idx += NTHR) {     // conv: 25 t x 32 f
                int tl = idx >> 5, f = idx & 31;
                float s = 0.f;
                for (int dw = 0; dw < 31; ++dw) {
                    s = fmaf(s_wwin[tl + dw], s_convw[(dw*2+0)*32 + f], s);
                    s = fmaf(s_cwin[tl + dw], s_convw[(dw*2+1)*32 + f], s);
                }
                s_co[tl*33 + f] = s;
            }
            __syncthreads();
            for (int idx = tid; idx < 3200; idx += NTHR) {    // dense+tanh+energy terms
                int tl = idx >> 7, a = idx & 127;
                float s = 0.f;
#pragma unroll
                for (int f = 0; f < 32; ++f) s = fmaf(s_co[tl*33 + f], s_ldense[f*128 + a], s);
                float loc = tanhf_(s);
                float en = tanhf_(s_q[a] + loc + pm[(b*200 + t0 + tl)*128 + a]);
                s_ea[idx] = en * s_v[a];
            }
            __syncthreads();
            if (tid < 200) {                                   // reduce over a, exp
                int tl = tid >> 3, ln = tid & 7;
                float s = 0.f;
                for (int a = ln; a < 128; a += 8) s += s_ea[tl*128 + a];
                s += __shfl_down(s, 4, 8);
                s += __shfl_down(s, 2, 8);
                s += __shfl_down(s, 1, 8);
                if (ln == 0) {
                    float ex = __expf(s);
                    eexp[b*200 + t0 + tl] = ex;
                    s_ex[tl] = ex;
                }
            }
            __syncthreads();
            if (tid == 0) {
                float s = 0.f;
                for (int i = 0; i < 25; ++i) s += s_ex[i];
                atomicAdd(&den[b], s);
            }
        }
        grid_barrier(bar, gen);

        // ---- S4: context = (e_exp @ memory)/den ; normalize att_w; cum; alignments ----
        {
            int b = blockIdx.x >> 3, dc = blockIdx.x & 7;
            int d = dc*64 + (tid & 63), tq = tid >> 6;
            float s = 0.f;
            for (int tt = tq*50; tt < tq*50 + 50; ++tt)
                s = fmaf(eexp[b*200 + tt], mp[(b*200 + tt)*512 + d], s);
            s_red[tid] = s;
            __syncthreads();
            if (tid < 64) {
                float cv = (s_red[tid] + s_red[64+tid] + s_red[128+tid] + s_red[192+tid]) / den[b];
                ctx[b*512 + d] = cv;
                in2T[(1024 + d)*32 + b] = cv;
                in1T[(256 + d)*32 + b] = cv;
            }
            if (dc == 0 && tid < 200) {
                float w = eexp[b*200 + tid] / den[b];
                attw[b*200 + tid] = w;
                cum[b*200 + tid] += w;
                out[OUT_ALIGN + (b*400 + t)*200 + tid] = w;
            }
        }
        grid_barrier(bar, gen);

        // ---- S5: LSTM2 gate partials ----
        gemv_block(l2k, l2r, KSPL2, in2T, zp, KC2);
        grid_barrier(bar, gen);

        // ---- S6: reduce -> h2,c2 ; projections ; stage x_{t+1} ----
        if (blockIdx.x < 32) {
            int b = blockIdx.x;
            for (int u = tid; u < 1024; u += NTHR) {
                float zi = l2b[u], zf = l2b[1024+u], zg = l2b[2048+u], zo = l2b[3072+u];
                for (int kc = 0; kc < 16; ++kc) {
                    const float* zr = zp + (kc*32 + b)*4096;
                    zi += zr[u]; zf += zr[1024+u]; zg += zr[2048+u]; zo += zr[3072+u];
                }
                float c = sigf(zf)*c2a[b*1024+u] + sigf(zi)*tanhf_(zg);
                float h = sigf(zo)*tanhf_(c);
                c2a[b*1024+u] = c;
                in2T[(1536+u)*32 + b] = h;
                s_hid[u] = h;
            }
            __syncthreads();
            float part = 0.f;
            if (tid < 240) {                         // mel = dhac @ frame_w + frame_b
                int kq = tid / 80, m = tid % 80;
                for (int k = kq*512; k < kq*512 + 512; ++k) {
                    float dv = (k < 1024) ? s_hid[k] : ctx[b*512 + (k - 1024)];
                    part = fmaf(dv, fw[k*80 + m], part);
                }
                s_red[tid] = part;
            }
            __syncthreads();
            if (tid < 80)
                out[(b*80 + tid)*400 + t] = fb[tid] + s_red[tid] + s_red[80+tid] + s_red[160+tid];
            __syncthreads();
            if (tid < 64) {                          // stop gate
                float sp = 0.f;
                for (int k = tid; k < 1536; k += 64) {
                    float dv = (k < 1024) ? s_hid[k] : ctx[b*512 + (k - 1024)];
                    sp = fmaf(dv, sw[k], sp);
                }
                for (int off = 32; off; off >>= 1) sp += __shfl_down(sp, off, 64);
                if (tid == 0) out[OUT_GATE + b*400 + t] = sigf(sp + sb[0]);
            }
        } else if (blockIdx.x < 64) {
            int b = blockIdx.x - 32;
            if (t + 1 < TSTEPS)
                in1T[tid*32 + b] = xpre[((t+1)*32 + b)*256 + tid];
        }
        grid_barrier(bar, gen);
    }
}

extern "C" void kernel_launch(void* const* d_in, const int* in_sizes, int n_in,
                              void* d_out, int out_size, void* d_ws, size_t ws_size,
                              hipStream_t stream) {
    (void)in_sizes; (void)n_in; (void)out_size;
    const float* mp    = (const float*)d_in[0];
    const float* dec   = (const float*)d_in[1];
    const float* pw0   = (const float*)d_in[2];
    const float* pb0   = (const float*)d_in[3];
    const float* pw1   = (const float*)d_in[4];
    const float* pb1   = (const float*)d_in[5];
    const float* l1k   = (const float*)d_in[6];
    const float* l1r   = (const float*)d_in[7];
    const float* l1b   = (const float*)d_in[8];
    const float* l2k   = (const float*)d_in[9];
    const float* l2r   = (const float*)d_in[10];
    const float* l2b   = (const float*)d_in[11];
    const float* wq    = (const float*)d_in[12];
    const float* wm    = (const float*)d_in[13];
    const float* vvec  = (const float*)d_in[14];
    const float* lconv = (const float*)d_in[15];
    const float* ldns  = (const float*)d_in[16];
    const float* fw    = (const float*)d_in[17];
    const float* fb    = (const float*)d_in[18];
    const float* sw    = (const float*)d_in[19];
    const float* sb    = (const float*)d_in[20];
    float* ws  = (float*)d_ws;
    float* out = (float*)d_out;

    if (ws_size < (size_t)WS_FLOATS * sizeof(float)) return;  // fail loudly (output stays wrong)

    prenet_kernel<<<dim3(400, 32), 256, 0, stream>>>(dec, pw0, pb0, pw1, pb1, ws);
    pmem_kernel  <<<dim3(200, 32), 128, 0, stream>>>(mp, wm, ws);
    decoder_loop <<<NBLK, NTHR, 0, stream>>>(mp, l1k, l1r, l1b, l2k, l2r, l2b,
                                             wq, vvec, lconv, ldns, fw, fb, sw, sb, ws, out);
}

// Round 2
// 150087.695 us; speedup vs baseline: 1.2579x; 1.2579x over previous
//
#include <hip/hip_runtime.h>
#include <math.h>

// ---------------- problem constants ----------------
#define TBATCH 32
#define TMEM   200
#define TSTEPS 400
#define DENC   512
#define DL     1024
#define G4     4096   // 4*DL
#define DATT   128
#define DPRE   256
#define NMEL   80
#define K1     1792   // 256 (x) + 512 (ctx) + 1024 (h1)
#define KSPL1  768    // rows in lstm1_k
#define KC1    112    // K1/16
#define K2     2560   // 1024 (h1) + 512 (ctx) + 1024 (h2)
#define KSPL2  1536   // rows in lstm2_k
#define KC2    160    // K2/16

#define NBLK 256
#define NTHR 1024     // 16 waves/CU: latency hiding for the weight stream

// ---------------- workspace layout (float offsets) ----------------
#define OFF_XPRE  0u
#define SZ_XPRE   (400u*32u*256u)            // prenet outputs [t][b][256]
#define OFF_PM    (OFF_XPRE + SZ_XPRE)
#define SZ_PM     (32u*200u*128u)            // tanh(memory@wm) [b][t][128]
#define OFF_IN1T  (OFF_PM + SZ_PM)
#define SZ_IN1T   (1792u*32u)                // lstm1 input, transposed [k][b]
#define OFF_IN2T  (OFF_IN1T + SZ_IN1T)
#define SZ_IN2T   (2560u*32u)                // lstm2 input, transposed [k][b]
#define OFF_ZP    (OFF_IN2T + SZ_IN2T)
#define SZ_ZP     (16u*32u*4096u)            // gate partials [kc][b][4096]
#define OFF_C1    (OFF_ZP + SZ_ZP)           // c1 [b][1024]
#define OFF_C2    (OFF_C1 + 32768u)          // c2
#define OFF_CTX   (OFF_C2 + 32768u)          // ctx [b][512]
#define OFF_ATTW  (OFF_CTX + 16384u)         // att_w [b][200]
#define OFF_CUM   (OFF_ATTW + 6400u)         // att_w_cum
#define OFF_EEXP  (OFF_CUM + 6400u)          // exp(energies)
#define OFF_Q     (OFF_EEXP + 6400u)         // q [b][128]
#define OFF_DEN   (OFF_Q + 4096u)            // softmax denom [b]
#define OFF_BAR   (OFF_DEN + 32u)            // barrier words
#define WS_FLOATS (OFF_BAR + 16u)

// output layout (floats)
#define OUT_GATE  1024000   // 32*80*400
#define OUT_ALIGN 1036800   // + 32*400

__device__ __forceinline__ float sigf(float x)   { return 1.f / (1.f + __expf(-x)); }
__device__ __forceinline__ float tanhf_(float x) { return 1.f - 2.f / (__expf(2.f*x) + 1.f); }

// ---------------- grid barrier (all 256 blocks resident) ----------------
__device__ __forceinline__ void grid_barrier(unsigned* bar, unsigned* gen) {
    __syncthreads();
    if (threadIdx.x == 0) {
        __threadfence();
        unsigned g = __hip_atomic_load(gen, __ATOMIC_RELAXED, __HIP_MEMORY_SCOPE_AGENT);
        unsigned t = __hip_atomic_fetch_add(bar, 1u, __ATOMIC_ACQ_REL, __HIP_MEMORY_SCOPE_AGENT);
        if (t == (unsigned)(NBLK - 1)) {
            __hip_atomic_store(bar, 0u, __ATOMIC_RELAXED, __HIP_MEMORY_SCOPE_AGENT);
            __hip_atomic_store(gen, g + 1u, __ATOMIC_RELEASE, __HIP_MEMORY_SCOPE_AGENT);
        } else {
            while (__hip_atomic_load(gen, __ATOMIC_RELAXED, __HIP_MEMORY_SCOPE_AGENT) == g)
                __builtin_amdgcn_s_sleep(2);
        }
        __threadfence();
    }
    __syncthreads();
}

// ---------------- P1: prenet for all 400 frames ----------------
__global__ void __launch_bounds__(256) prenet_kernel(
    const float* __restrict__ dec, const float* __restrict__ w0, const float* __restrict__ b0,
    const float* __restrict__ w1, const float* __restrict__ b1, float* __restrict__ ws)
{
    __shared__ float s_in[80];
    __shared__ float s_h0[256];
    int t = blockIdx.x, b = blockIdx.y, tid = threadIdx.x;
    if (tid < 80) s_in[tid] = (t == 0) ? 0.f : dec[b*32000 + tid*400 + (t-1)];
    if (blockIdx.x == 0 && blockIdx.y == 0 && tid < 4)
        ((unsigned*)(ws + OFF_BAR))[tid] = 0u;   // zero barrier words each call
    __syncthreads();
    float s = b0[tid];
    for (int m = 0; m < 80; ++m) s = fmaf(s_in[m], w0[m*256 + tid], s);
    s_h0[tid] = fmaxf(s, 0.f);
    __syncthreads();
    float s2 = b1[tid];
    for (int k = 0; k < 256; ++k) s2 = fmaf(s_h0[k], w1[k*256 + tid], s2);
    ws[OFF_XPRE + (t*32 + b)*256 + tid] = fmaxf(s2, 0.f);
}

// ---------------- P2: processed_memory = tanh(memory @ wm) ----------------
__global__ void __launch_bounds__(128) pmem_kernel(
    const float* __restrict__ mp, const float* __restrict__ wm, float* __restrict__ ws)
{
    int t = blockIdx.x, b = blockIdx.y, a = threadIdx.x;
    const float* mrow = mp + (b*200 + t)*512;
    float s = 0.f;
    for (int d = 0; d < 512; ++d) s = fmaf(mrow[d], wm[d*128 + a], s);
    ws[OFF_PM + (b*200 + t)*128 + a] = tanhf_(s);
}

// ---------------- GEMV partial ----------------
// 256 blocks = 16 jb x 16 kc. 1024 threads = 16 bgrp(x2 batch) x 64 jgrp(x4 cols).
// Per k: 1 float4 weight load (coalesced 1KB/wave) + 1 float2 input broadcast,
// 8 FMAs. unroll 4 -> ~4 weight loads in flight per wave.
__device__ __forceinline__ void gemv_block(
    const float* __restrict__ Wk, const float* __restrict__ Wr, int ksplit,
    const float* __restrict__ inT, float* __restrict__ zp, int kcsize)
{
    const int jb = blockIdx.x >> 4, kc = blockIdx.x & 15;
    const int jgrp = threadIdx.x & 63;
    const int bgrp = threadIdx.x >> 6;
    const int j = (jb << 8) + (jgrp << 2);
    const int b0 = bgrp << 1;
    float4 a0 = {0.f,0.f,0.f,0.f}, a1 = {0.f,0.f,0.f,0.f};
    const int k0 = kc * kcsize, k1 = k0 + kcsize;
    const int ka = min(k1, ksplit);
#pragma unroll 4
    for (int k = k0; k < ka; ++k) {
        float4 w = *(const float4*)(Wk + k*4096 + j);
        float2 x = *(const float2*)(inT + k*32 + b0);
        a0.x = fmaf(x.x, w.x, a0.x); a0.y = fmaf(x.x, w.y, a0.y);
        a0.z = fmaf(x.x, w.z, a0.z); a0.w = fmaf(x.x, w.w, a0.w);
        a1.x = fmaf(x.y, w.x, a1.x); a1.y = fmaf(x.y, w.y, a1.y);
        a1.z = fmaf(x.y, w.z, a1.z); a1.w = fmaf(x.y, w.w, a1.w);
    }
    const int kb = max(k0, ksplit);
#pragma unroll 4
    for (int k = kb; k < k1; ++k) {
        float4 w = *(const float4*)(Wr + (k - ksplit)*4096 + j);
        float2 x = *(const float2*)(inT + k*32 + b0);
        a0.x = fmaf(x.x, w.x, a0.x); a0.y = fmaf(x.x, w.y, a0.y);
        a0.z = fmaf(x.x, w.z, a0.z); a0.w = fmaf(x.x, w.w, a0.w);
        a1.x = fmaf(x.y, w.x, a1.x); a1.y = fmaf(x.y, w.y, a1.y);
        a1.z = fmaf(x.y, w.z, a1.z); a1.w = fmaf(x.y, w.w, a1.w);
    }
    float* zr = zp + (kc*32 + b0)*4096 + j;
    *(float4*)zr = a0;
    *(float4*)(zr + 4096) = a1;
}

// ---------------- persistent decoder loop ----------------
__global__ void __launch_bounds__(NTHR) decoder_loop(
    const float* __restrict__ mp,
    const float* __restrict__ l1k, const float* __restrict__ l1r, const float* __restrict__ l1b,
    const float* __restrict__ l2k, const float* __restrict__ l2r, const float* __restrict__ l2b,
    const float* __restrict__ wq, const float* __restrict__ vvec,
    const float* __restrict__ lconv, const float* __restrict__ ldense,
    const float* __restrict__ fw, const float* __restrict__ fb,
    const float* __restrict__ sw, const float* __restrict__ sb,
    float* __restrict__ ws, float* __restrict__ out)
{
    __shared__ float s_convw[31*2*32];
    __shared__ float s_ldense[32*128];
    __shared__ float s_v[128];
    __shared__ float s_wwin[56], s_cwin[56];
    __shared__ float s_co[25*33];
    __shared__ float s_ea[25*128];
    __shared__ float s_q[128];
    __shared__ float s_ex[32];
    __shared__ float s_hid[1024];
    __shared__ float s_red[1024];

    float* xpre = ws + OFF_XPRE;
    float* pm   = ws + OFF_PM;
    float* in1T = ws + OFF_IN1T;
    float* in2T = ws + OFF_IN2T;
    float* zp   = ws + OFF_ZP;
    float* c1a  = ws + OFF_C1;
    float* c2a  = ws + OFF_C2;
    float* ctx  = ws + OFF_CTX;
    float* attw = ws + OFF_ATTW;
    float* cum  = ws + OFF_CUM;
    float* eexp = ws + OFF_EEXP;
    float* qarr = ws + OFF_Q;
    float* den  = ws + OFF_DEN;
    unsigned* bar = (unsigned*)(ws + OFF_BAR);
    unsigned* gen = bar + 1;

    const int tid = threadIdx.x;
    const int gid = blockIdx.x * NTHR + tid;
    const int gsz = NBLK * NTHR;

    // persistent LDS fill
    for (int i = tid; i < 1984; i += NTHR) s_convw[i] = lconv[i];
    for (int i = tid; i < 4096; i += NTHR) s_ldense[i] = ldense[i];
    if (tid < 128) s_v[tid] = vvec[tid];

    // ---- init (ws is poisoned before every call) ----
    for (int i = gid; i < (int)SZ_IN1T - 256*32; i += gsz) in1T[256*32 + i] = 0.f;
    for (int i = gid; i < (int)SZ_IN2T; i += gsz) in2T[i] = 0.f;
    for (int i = gid; i < 32768; i += gsz) { c1a[i] = 0.f; c2a[i] = 0.f; }
    for (int i = gid; i < 6400;  i += gsz) { attw[i] = 0.f; cum[i] = 0.f; }
    for (int i = gid; i < 8192;  i += gsz) {
        int k = i >> 5, b = i & 31;
        in1T[i] = xpre[b*256 + k];
    }
    grid_barrier(bar, gen);

#pragma unroll 1
    for (int t = 0; t < TSTEPS; ++t) {
        // ---- S1: LSTM1 gate partials ----
        gemv_block(l1k, l1r, KSPL1, in1T, zp, KC1);
        grid_barrier(bar, gen);

        // ---- S2: reduce -> gates -> h1,c1 ; q = tanh(h1@wq) ----
        if (blockIdx.x < 32) {
            int b = blockIdx.x;
            {
                int u = tid;    // 1024 threads: one u each
                float zi = l1b[u], zf = l1b[1024+u], zg = l1b[2048+u], zo = l1b[3072+u];
#pragma unroll 4
                for (int kc = 0; kc < 16; ++kc) {
                    const float* zr = zp + (kc*32 + b)*4096;
                    zi += zr[u]; zf += zr[1024+u]; zg += zr[2048+u]; zo += zr[3072+u];
                }
                float c = sigf(zf)*c1a[b*1024+u] + sigf(zi)*tanhf_(zg);
                float h = sigf(zo)*tanhf_(c);
                c1a[b*1024+u] = c;
                in1T[(768+u)*32 + b] = h;
                in2T[u*32 + b] = h;
                s_hid[u] = h;
            }
            if (tid == 0) den[b] = 0.f;
            __syncthreads();
            {
                int a = tid & 127, kq = tid >> 7;   // 8 k-chunks of 128
                float s = 0.f;
                for (int k = kq*128; k < kq*128 + 128; ++k)
                    s = fmaf(s_hid[k], wq[k*128 + a], s);
                s_red[tid] = s;
            }
            __syncthreads();
            if (tid < 128) {
                float s = 0.f;
#pragma unroll
                for (int q = 0; q < 8; ++q) s += s_red[q*128 + tid];
                qarr[b*128 + tid] = tanhf_(s);
            }
        }
        grid_barrier(bar, gen);

        // ---- S3: location attention -> exp(energies), partial denom ----
        {
            int b = blockIdx.x >> 3, tc = blockIdx.x & 7;
            int t0 = tc * 25;
            if (tid < 56)      { int tg = t0 - 15 + tid; s_wwin[tid] = (tg >= 0 && tg < 200) ? attw[b*200 + tg] : 0.f; }
            else if (tid < 112){ int i = tid - 56; int tg = t0 - 15 + i; s_cwin[i] = (tg >= 0 && tg < 200) ? cum[b*200 + tg] : 0.f; }
            else if (tid >= 112 && tid < 240) { int a = tid - 112; if (a < 128) s_q[a] = qarr[b*128 + a]; }
            __syncthreads();
            for (int idx = tid; idx < 800; idx += NTHR) {
                int tl = idx >> 5, f = idx & 31;
                float s = 0.f;
                for (int dw = 0; dw < 31; ++dw) {
                    s = fmaf(s_wwin[tl + dw], s_convw[(dw*2+0)*32 + f], s);
                    s = fmaf(s_cwin[tl + dw], s_convw[(dw*2+1)*32 + f], s);
                }
                s_co[tl*33 + f] = s;
            }
            __syncthreads();
            for (int idx = tid; idx < 3200; idx += NTHR) {
                int tl = idx >> 7, a = idx & 127;
                float s = 0.f;
#pragma unroll
                for (int f = 0; f < 32; ++f) s = fmaf(s_co[tl*33 + f], s_ldense[f*128 + a], s);
                float loc = tanhf_(s);
                float en = tanhf_(s_q[a] + loc + pm[(b*200 + t0 + tl)*128 + a]);
                s_ea[idx] = en * s_v[a];
            }
            __syncthreads();
            if (tid < 200) {
                int tl = tid >> 3, ln = tid & 7;
                float s = 0.f;
                for (int a = ln; a < 128; a += 8) s += s_ea[tl*128 + a];
                s += __shfl_down(s, 4, 8);
                s += __shfl_down(s, 2, 8);
                s += __shfl_down(s, 1, 8);
                if (ln == 0) {
                    float ex = __expf(s);
                    eexp[b*200 + t0 + tl] = ex;
                    s_ex[tl] = ex;
                }
            }
            __syncthreads();
            if (tid == 0) {
                float s = 0.f;
                for (int i = 0; i < 25; ++i) s += s_ex[i];
                atomicAdd(&den[b], s);
            }
        }
        grid_barrier(bar, gen);

        // ---- S4: context = (e_exp @ memory)/den ; normalize att_w; cum; alignments ----
        {
            int b = blockIdx.x >> 3, dc = blockIdx.x & 7;
            int dl = tid & 63, tq = tid >> 6;     // 16 t-chunks of 13
            int d = dc*64 + dl;
            float s = 0.f;
            int te = min(200, tq*13 + 13);
            for (int tt = tq*13; tt < te; ++tt)
                s = fmaf(eexp[b*200 + tt], mp[(b*200 + tt)*512 + d], s);
            s_red[tid] = s;
            __syncthreads();
            if (tid < 64) {
                float cv = 0.f;
#pragma unroll
                for (int q = 0; q < 16; ++q) cv += s_red[q*64 + tid];
                cv /= den[b];
                int dd = dc*64 + tid;
                ctx[b*512 + dd] = cv;
                in2T[(1024 + dd)*32 + b] = cv;
                in1T[(256 + dd)*32 + b] = cv;
            }
            if (dc == 0 && tid >= 512 && tid < 712) {
                int tt = tid - 512;
                float w = eexp[b*200 + tt] / den[b];
                attw[b*200 + tt] = w;
                cum[b*200 + tt] += w;
                out[OUT_ALIGN + (b*400 + t)*200 + tt] = w;
            }
        }
        grid_barrier(bar, gen);

        // ---- S5: LSTM2 gate partials ----
        gemv_block(l2k, l2r, KSPL2, in2T, zp, KC2);
        grid_barrier(bar, gen);

        // ---- S6: reduce -> h2,c2 ; projections ; stage x_{t+1} ----
        if (blockIdx.x < 32) {
            int b = blockIdx.x;
            {
                int u = tid;
                float zi = l2b[u], zf = l2b[1024+u], zg = l2b[2048+u], zo = l2b[3072+u];
#pragma unroll 4
                for (int kc = 0; kc < 16; ++kc) {
                    const float* zr = zp + (kc*32 + b)*4096;
                    zi += zr[u]; zf += zr[1024+u]; zg += zr[2048+u]; zo += zr[3072+u];
                }
                float c = sigf(zf)*c2a[b*1024+u] + sigf(zi)*tanhf_(zg);
                float h = sigf(zo)*tanhf_(c);
                c2a[b*1024+u] = c;
                in2T[(1536+u)*32 + b] = h;
                s_hid[u] = h;
            }
            __syncthreads();
            if (tid < 240) {
                int kq = tid / 80, m = tid % 80;
                float part = 0.f;
                for (int k = kq*512; k < kq*512 + 512; ++k) {
                    float dv = (k < 1024) ? s_hid[k] : ctx[b*512 + (k - 1024)];
                    part = fmaf(dv, fw[k*80 + m], part);
                }
                s_red[tid] = part;
            }
            __syncthreads();
            if (tid < 80)
                out[(b*80 + tid)*400 + t] = fb[tid] + s_red[tid] + s_red[80+tid] + s_red[160+tid];
            if (tid >= 256 && tid < 320) {          // stop gate (separate wave)
                int ln = tid - 256;
                float sp = 0.f;
                for (int k = ln; k < 1536; k += 64) {
                    float dv = (k < 1024) ? s_hid[k] : ctx[b*512 + (k - 1024)];
                    sp = fmaf(dv, sw[k], sp);
                }
                for (int off = 32; off; off >>= 1) sp += __shfl_down(sp, off, 64);
                if (ln == 0) out[OUT_GATE + b*400 + t] = sigf(sp + sb[0]);
            }
        } else if (blockIdx.x < 64) {
            int b = blockIdx.x - 32;
            if (t + 1 < TSTEPS && tid < 256)
                in1T[tid*32 + b] = xpre[((t+1)*32 + b)*256 + tid];
        }
        grid_barrier(bar, gen);
    }
}

extern "C" void kernel_launch(void* const* d_in, const int* in_sizes, int n_in,
                              void* d_out, int out_size, void* d_ws, size_t ws_size,
                              hipStream_t stream) {
    (void)in_sizes; (void)n_in; (void)out_size;
    const float* mp    = (const float*)d_in[0];
    const float* dec   = (const float*)d_in[1];
    const float* pw0   = (const float*)d_in[2];
    const float* pb0   = (const float*)d_in[3];
    const float* pw1   = (const float*)d_in[4];
    const float* pb1   = (const float*)d_in[5];
    const float* l1k   = (const float*)d_in[6];
    const float* l1r   = (const float*)d_in[7];
    const float* l1b   = (const float*)d_in[8];
    const float* l2k   = (const float*)d_in[9];
    const float* l2r   = (const float*)d_in[10];
    const float* l2b   = (const float*)d_in[11];
    const float* wq    = (const float*)d_in[12];
    const float* wm    = (const float*)d_in[13];
    const float* vvec  = (const float*)d_in[14];
    const float* lconv = (const float*)d_in[15];
    const float* ldns  = (const float*)d_in[16];
    const float* fw    = (const float*)d_in[17];
    const float* fb    = (const float*)d_in[18];
    const float* sw    = (const float*)d_in[19];
    const float* sb    = (const float*)d_in[20];
    float* ws  = (float*)d_ws;
    float* out = (float*)d_out;

    if (ws_size < (size_t)WS_FLOATS * sizeof(float)) return;

    prenet_kernel<<<dim3(400, 32), 256, 0, stream>>>(dec, pw0, pb0, pw1, pb1, ws);
    pmem_kernel  <<<dim3(200, 32), 128, 0, stream>>>(mp, wm, ws);
    decoder_loop <<<NBLK, NTHR, 0, stream>>>(mp, l1k, l1r, l1b, l2k, l2r, l2b,
                                             wq, vvec, lconv, ldns, fw, fb, sw, sb, ws, out);
}